// Round 6
// baseline (288.347 us; speedup 1.0000x reference)
//
#include <hip/hip_runtime.h>
#include <hip/hip_bf16.h>

#define Bz 64
#define Tz 512
#define Dz 1024
#define Kz 32

#define MOFF 128
#define LOFF (128 + 1024 * 1024)

typedef __attribute__((ext_vector_type(8)))  __bf16 bf16x8;
typedef __attribute__((ext_vector_type(16))) float  f32x16;

__device__ __forceinline__ float bcast_lane(float x, int i) {
    return __uint_as_float(__builtin_amdgcn_readlane(__float_as_uint(x), i));
}

// pack two f32 into bf16x2 (lo -> bits 0..15, hi -> bits 16..31), round-half-up
__device__ __forceinline__ unsigned pack2bf(float lo, float hi) {
    return __builtin_amdgcn_perm(__float_as_uint(hi) + 0x8000u,
                                 __float_as_uint(lo) + 0x8000u, 0x07060302u);
}

union BfCast { unsigned u[4]; bf16x8 v; };

// ---------------------------------------------------------------------------
// Kernel 1: logits[32768][32] = V @ W^T + b  via bf16 MFMA 32x32x16.
// 1024 blocks x 256 thr; block = 32 rows; wave wv owns K-quarter.
// V staged global->LDS with PERFECTLY COALESCED reads (1 KB contiguous per
// wave instr) into a pad-4 [32][260] tile (stride%32==4 -> both LDS write
// and b128 A-frag read are at the balanced 8-round floor, no conflicts).
// Register-prefetch of next chunk overlaps compute. W B-frags in 64 VGPRs.
// ~135 VGPR + 33 KB LDS -> 3 blocks/CU = 12 waves/CU.
// ---------------------------------------------------------------------------
__global__ __launch_bounds__(256) void logits_kernel(
        const float* __restrict__ V, const float* __restrict__ W,
        const float* __restrict__ bias, float* __restrict__ out) {
    __shared__ float vt[32 * 260];   // 33.3 KB, row stride 260 floats

    const int tid  = threadIdx.x;
    const int wv   = tid >> 6;          // K-quarter index
    const int lane = tid & 63;
    const int n    = lane & 31;
    const int h    = lane >> 5;
    const int r0   = blockIdx.x * 32;

    // ---- preload W B-frags: (chunk c, step i) -> cols c*256+(4wv+i)*16+h*8
    BfCast wf[16];
    #pragma unroll
    for (int c = 0; c < 4; ++c) {
        #pragma unroll
        for (int i = 0; i < 4; ++i) {
            const float* wp = W + (size_t)n * Dz + c * 256 + (4 * wv + i) * 16 + h * 8;
            const float4 w0 = *(const float4*)wp;
            const float4 w1 = *(const float4*)(wp + 4);
            wf[c * 4 + i].u[0] = pack2bf(w0.x, w0.y);
            wf[c * 4 + i].u[1] = pack2bf(w0.z, w0.w);
            wf[c * 4 + i].u[2] = pack2bf(w1.x, w1.y);
            wf[c * 4 + i].u[3] = pack2bf(w1.z, w1.w);
        }
    }

    // ---- coalesced V staging: thread's float4 slot f = tid + k*256,
    //      row = f>>6 (64 float4/row), col4 = f&63. One wave instr = 1 row = 1 KB.
    const float* vbase = V + (size_t)r0 * Dz;
    float4 sg[8];
    #pragma unroll
    for (int k = 0; k < 8; ++k) {
        const int f = tid + k * 256;
        sg[k] = *(const float4*)(vbase + (size_t)(f >> 6) * Dz + (f & 63) * 4);
    }

    f32x16 acc;
    #pragma unroll
    for (int i = 0; i < 16; ++i) acc[i] = 0.f;

    #pragma unroll
    for (int c = 0; c < 4; ++c) {
        // stage regs -> LDS (balanced banks: base = 4*(row+col4) mod 32)
        #pragma unroll
        for (int k = 0; k < 8; ++k) {
            const int f = tid + k * 256;
            *(float4*)&vt[(f >> 6) * 260 + (f & 63) * 4] = sg[k];
        }
        __syncthreads();
        // prefetch next chunk into regs (in flight during compute)
        if (c + 1 < 4) {
            #pragma unroll
            for (int k = 0; k < 8; ++k) {
                const int f = tid + k * 256;
                sg[k] = *(const float4*)(vbase + (size_t)(f >> 6) * Dz +
                                         (c + 1) * 256 + (f & 63) * 4);
            }
        }
        // compute: 4 MFMA steps on this wave's K-quarter of the chunk
        #pragma unroll
        for (int i = 0; i < 4; ++i) {
            const float* ap = &vt[n * 260 + (4 * wv + i) * 16 + h * 8];
            const float4 a0 = *(const float4*)ap;
            const float4 a1 = *(const float4*)(ap + 4);
            BfCast cA;
            cA.u[0] = pack2bf(a0.x, a0.y);
            cA.u[1] = pack2bf(a0.z, a0.w);
            cA.u[2] = pack2bf(a1.x, a1.y);
            cA.u[3] = pack2bf(a1.z, a1.w);
            acc = __builtin_amdgcn_mfma_f32_32x32x16_bf16(cA.v, wf[c * 4 + i].v, acc, 0, 0, 0);
        }
        __syncthreads();
    }

    // ---- combine the 4 K-quarter partials (reuse vt as scratch)
    if (wv > 0) {
        #pragma unroll
        for (int i = 0; i < 16; ++i)
            vt[(wv - 1) * 1024 + i * 64 + lane] = acc[i];
    }
    __syncthreads();
    if (wv == 0) {
        const float bv = bias[n];
        #pragma unroll
        for (int i = 0; i < 16; ++i) {
            const float s = ((acc[i] + vt[i * 64 + lane]) +
                             (vt[1024 + i * 64 + lane] + vt[2048 + i * 64 + lane])) + bv;
            const int row = (i & 3) + 8 * (i >> 2) + 4 * h;   // C/D layout
            out[(size_t)(r0 + row) * Kz + n] = s;
        }
    }
}

// ---------------------------------------------------------------------------
// Kernel 2a: per-(batch,segment) 32x32 CRF transfer-matrix product via MFMA.
// X <- (diag(E_t)*ET^T) * X ; E folded into A (lane-local). Rescale every 8
// steps (growth <= e^54, safe in f32/bf16 exponent range).
// 1024 blocks (b*16+s) x 64 threads. No barriers in the main loop.
// ---------------------------------------------------------------------------
__global__ __launch_bounds__(64) void crf_seg_kernel(
        const float* __restrict__ logits, const float* __restrict__ trans,
        float* __restrict__ ws) {
    __shared__ float xpose[33 * 32];

    const int bid  = blockIdx.x;
    const int b    = bid >> 4;
    const int seg  = bid & 15;
    const int lane = threadIdx.x;
    const int n    = lane & 31;
    const int h    = lane >> 5;

    int rIdx[16];
    #pragma unroll
    for (int i = 0; i < 16; ++i) rIdx[i] = (i & 3) + 8 * (i >> 2) + 4 * h;

    float etf[16];
    #pragma unroll
    for (int i = 0; i < 16; ++i) etf[i] = __expf(trans[rIdx[i] * Kz + n]);

    const float* lg = logits + ((size_t)b * Tz + (size_t)seg * 32) * Kz;
    float Ev[32];
    #pragma unroll
    for (int u = 0; u < 32; ++u) Ev[u] = __expf(lg[u * Kz + n]);

    unsigned bu[8];
    #pragma unroll
    for (int q = 0; q < 4; ++q) {
        bu[q] = ((rIdx[2 * q] == n) ? 0x3F80u : 0u) |
                (((rIdx[2 * q + 1] == n) ? 0x3F80u : 0u) << 16);
        bu[4 + q] = ((rIdx[8 + 2 * q] == n) ? 0x3F80u : 0u) |
                    (((rIdx[8 + 2 * q + 1] == n) ? 0x3F80u : 0u) << 16);
    }

    f32x16 zf;
    #pragma unroll
    for (int i = 0; i < 16; ++i) zf[i] = 0.f;

    float Xs[16];
    #pragma unroll
    for (int i = 0; i < 16; ++i) Xs[i] = (rIdx[i] == n) ? 1.f : 0.f;
    float lsc = 0.f;

    #pragma unroll
    for (int u = 0; u < 32; ++u) {
        if (u > 0 || seg > 0) {
            const float E = Ev[u];
            BfCast cA1, cA2, cB1, cB2;
            #pragma unroll
            for (int q = 0; q < 4; ++q) {
                cA1.u[q] = pack2bf(E * etf[2 * q], E * etf[2 * q + 1]);
                cA2.u[q] = pack2bf(E * etf[8 + 2 * q], E * etf[8 + 2 * q + 1]);
                cB1.u[q] = bu[q];
                cB2.u[q] = bu[4 + q];
            }
            f32x16 acc = __builtin_amdgcn_mfma_f32_32x32x16_bf16(cA1.v, cB1.v, zf, 0, 0, 0);
            acc = __builtin_amdgcn_mfma_f32_32x32x16_bf16(cA2.v, cB2.v, acc, 0, 0, 0);
            #pragma unroll
            for (int i = 0; i < 16; ++i) Xs[i] = acc[i];
            if ((u & 7) == 7) {   // uniform rescale (hits u==31 -> stored P bounded)
                float m = Xs[0];
                #pragma unroll
                for (int i = 1; i < 16; ++i) m = fmaxf(m, Xs[i]);
                #pragma unroll
                for (int dd = 1; dd < 64; dd <<= 1) m = fmaxf(m, __shfl_xor(m, dd, 64));
                const float r = __builtin_amdgcn_rcpf(m);
                lsc += __logf(m);
                #pragma unroll
                for (int i = 0; i < 16; ++i) Xs[i] *= r;
            }
            #pragma unroll
            for (int q = 0; q < 4; ++q) {
                bu[q]     = pack2bf(Xs[2 * q], Xs[2 * q + 1]);
                bu[4 + q] = pack2bf(Xs[8 + 2 * q], Xs[8 + 2 * q + 1]);
            }
        }
    }

    #pragma unroll
    for (int i = 0; i < 16; ++i)
        xpose[n * 33 + rIdx[i]] = Xs[i];   // P[n][rIdx[i]]
    __syncthreads();
    float* mout = ws + MOFF + (size_t)bid * 1024;
    #pragma unroll
    for (int k = 0; k < 16; ++k) {
        const int row = 2 * k + h;
        mout[row * 32 + n] = xpose[row * 33 + n];
    }
    if (lane == 0) ws[LOFF + bid] = lsc;
}

// ---------------------------------------------------------------------------
// Kernel 2b: combine — alpha through 16 segment matrices + gold score.
// 64 blocks x 64 threads. P prefetched one segment ahead.
// ---------------------------------------------------------------------------
__global__ __launch_bounds__(64) void crf_combine_kernel(
        const float* __restrict__ logits, const int* __restrict__ mask,
        const int* __restrict__ targets, const float* __restrict__ trans,
        const float* __restrict__ start_t, const float* __restrict__ end_t,
        float* __restrict__ ws) {
    const int b    = blockIdx.x;
    const int lane = threadIdx.x;
    const int n    = lane & 31;

    const float* lg = logits + (size_t)b * Tz * Kz;
    const int*   tg = targets + b * Tz;
    const int*   mk = mask + b * Tz;

    float emit_s = 0.f, trans_s = 0.f, msum = 0.f;
    for (int t = lane; t < Tz; t += 64) {
        const int   tt = tg[t];
        const float m  = (float)mk[t];
        emit_s += lg[t * Kz + tt] * m;
        if (t > 0) trans_s += trans[tg[t - 1] * Kz + tt] * m;
        msum += m;
    }
    float ssum = emit_s + trans_s;
    #pragma unroll
    for (int dd = 1; dd < 64; dd <<= 1) {
        ssum += __shfl_xor(ssum, dd, 64);
        msum += __shfl_xor(msum, dd, 64);
    }

    float al = start_t[n] + lg[n];
    float m0 = al;
    #pragma unroll
    for (int dd = 1; dd < 32; dd <<= 1) m0 = fmaxf(m0, __shfl_xor(m0, dd, 64));
    float v    = __expf(al - m0);
    float lacc = m0;

    const float* Pb = ws + MOFF + (size_t)b * 16 * 1024;
    float pv[32];
    #pragma unroll
    for (int i = 0; i < 32; ++i) pv[i] = Pb[i * 32 + n];

    #pragma unroll
    for (int s = 0; s < 16; ++s) {
        float pn[32];
        if (s + 1 < 16) {
            const float* Pn = Pb + (size_t)(s + 1) * 1024;
            #pragma unroll
            for (int i = 0; i < 32; ++i) pn[i] = Pn[i * 32 + n];
        }
        float n0 = 0.f, n1 = 0.f, n2 = 0.f, n3 = 0.f;
        #pragma unroll
        for (int i = 0; i < 32; i += 4) {
            n0 = fmaf(bcast_lane(v, i + 0), pv[i + 0], n0);
            n1 = fmaf(bcast_lane(v, i + 1), pv[i + 1], n1);
            n2 = fmaf(bcast_lane(v, i + 2), pv[i + 2], n2);
            n3 = fmaf(bcast_lane(v, i + 3), pv[i + 3], n3);
        }
        v = (n0 + n1) + (n2 + n3);
        lacc += ws[LOFF + b * 16 + s];
        float mm = v;
        #pragma unroll
        for (int dd = 1; dd < 32; dd <<= 1) mm = fmaxf(mm, __shfl_xor(mm, dd, 64));
        v *= __builtin_amdgcn_rcpf(mm);
        lacc += __logf(mm);
        if (s + 1 < 16) {
            #pragma unroll
            for (int i = 0; i < 32; ++i) pv[i] = pn[i];
        }
    }

    float w  = v * __expf(end_t[n]);
    float sv = w;
    #pragma unroll
    for (int dd = 1; dd < 32; dd <<= 1) sv += __shfl_xor(sv, dd, 64);
    const float part = lacc + __logf(sv);

    if (lane == 0) {
        const int lastIdx = (int)msum - 1;
        const float score = start_t[tg[0]] + ssum + end_t[tg[lastIdx]];
        ws[b]      = score - part;
        ws[64 + b] = msum;
    }
}

// ---------------------------------------------------------------------------
// Kernel 3: loss = -sum_b(score_b - part_b) / sum(mask)
// ---------------------------------------------------------------------------
__global__ __launch_bounds__(64) void crf_final_kernel(
        const float* __restrict__ ws, float* __restrict__ out) {
    const int lane = threadIdx.x;
    float p    = ws[lane];
    float msum = ws[64 + lane];
    #pragma unroll
    for (int dd = 1; dd < 64; dd <<= 1) {
        p    += __shfl_xor(p, dd, 64);
        msum += __shfl_xor(msum, dd, 64);
    }
    if (lane == 0) out[0] = -p / msum;
}

extern "C" void kernel_launch(void* const* d_in, const int* in_sizes, int n_in,
                              void* d_out, int out_size, void* d_ws, size_t ws_size,
                              hipStream_t stream) {
    const float* V       = (const float*)d_in[0];
    const int*   mask    = (const int*)d_in[1];
    const int*   targets = (const int*)d_in[2];
    const float* W       = (const float*)d_in[3];
    const float* bias    = (const float*)d_in[4];
    const float* trans   = (const float*)d_in[5];
    const float* start_t = (const float*)d_in[6];
    const float* end_t   = (const float*)d_in[7];

    float* out = (float*)d_out;   // out[0] = loss, out[1..] = logits [B,T,K]
    float* ws  = (float*)d_ws;    // ~4.2 MB used

    logits_kernel<<<1024, 256, 0, stream>>>(V, W, bias, out + 1);
    crf_seg_kernel<<<1024, 64, 0, stream>>>(out + 1, trans, ws);
    crf_combine_kernel<<<64, 64, 0, stream>>>(out + 1, mask, targets, trans,
                                              start_t, end_t, ws);
    crf_final_kernel<<<1, 64, 0, stream>>>(ws, out);
}